// Round 9
// baseline (1775.548 us; speedup 1.0000x reference)
//
#include <hip/hip_runtime.h>
#include <hip/hip_bf16.h>
#include <stdint.h>

// DeepFakeDetectionModel: stem LN(26)->Linear(26->1024)->ReLU, 8x [LN->Linear(1024->1024)->ReLU],
// head LN->Linear(1024->1)->sigmoid.  B=65536.
//
// LN folded into weights (W'=gamma*W fp16, S'=sum W', b'=b+beta@W^T); GEMMs run on RAW fp16
// activations; LN affine applied in epilogue from per-row (sum,sumsq) stats.
// R2: T2 swizzle. R3: XCD swizzle (FETCH 136->49.5MB). R4-R7: schedule/occupancy variants all
//     plateau ~755 TF; invariant = B through LDS => 12 ds_reads + 6 staging loads + full-block
//     barrier-synced bursts per 32-K-step.
// R8: B direct L2->registers (W is 2MB, L2-resident; MFMA B-frag is exactly one
//     global_load_dwordx4 per lane). LDS holds A only (16KB/block). Counted-vmcnt FIFO:
//     per tile issue [A-lds(kt+1) x2, B-glb(kt+1) x4]; pre-MFMA vmcnt(6) (B(kt) ready);
//     boundary vmcnt(4)+barrier (A(kt+1) ready, B(kt+1) in flight). vmcnt(0) only at tail.
//     B regs double-buffered via even/odd peel (static indexing).

typedef __attribute__((ext_vector_type(8))) _Float16 f16x8;
typedef __attribute__((ext_vector_type(4))) float f32x4;

#define EPSLN 1e-5f
#define HDIM 1024

__device__ __forceinline__ void gload16(const void* g, void* l) {
  __builtin_amdgcn_global_load_lds(
      (const __attribute__((address_space(1))) unsigned int*)g,
      (__attribute__((address_space(3))) unsigned int*)l, 16, 0, 0);
}

// ---------------- zero stats ----------------
__global__ __launch_bounds__(256) void zero_f32(float* __restrict__ p, int n) {
  int i = blockIdx.x * 256 + threadIdx.x;
  if (i < n) p[i] = 0.f;
}

// ---------------- fold block weights ----------------
__global__ __launch_bounds__(256) void fold_blk(
    const float* __restrict__ bg, const float* __restrict__ bb,
    const float* __restrict__ bw, const float* __restrict__ bbias,
    _Float16* __restrict__ Wf, float* __restrict__ bfold, float* __restrict__ Sfold) {
  int lo = blockIdx.x;            // layer*1024 + o
  int layer = lo >> 10;
  const float* wrow = bw + (size_t)lo * HDIM;
  const float* g = bg + (size_t)layer * HDIM;
  const float* be = bb + (size_t)layer * HDIM;
  _Float16* wout = Wf + (size_t)lo * HDIM;
  int t = threadIdx.x;
  float s = 0.f, acb = 0.f;
  for (int i = t; i < HDIM; i += 256) {
    float wv = wrow[i];
    _Float16 wp = (_Float16)(wv * g[i]);
    wout[i] = wp;
    s += (float)wp;               // S' from ROUNDED weights (consistency with GEMM)
    acb += be[i] * wv;
  }
#pragma unroll
  for (int off = 1; off < 64; off <<= 1) { s += __shfl_xor(s, off); acb += __shfl_xor(acb, off); }
  __shared__ float rs[4], rb[4];
  int l = t & 63, w = t >> 6;
  if (l == 0) { rs[w] = s; rb[w] = acb; }
  __syncthreads();
  if (t == 0) {
    Sfold[lo] = rs[0] + rs[1] + rs[2] + rs[3];
    bfold[lo] = bbias[lo] + rb[0] + rb[1] + rb[2] + rb[3];
  }
}

// ---------------- fold head ----------------
__global__ __launch_bounds__(256) void fold_head(
    const float* __restrict__ lg, const float* __restrict__ lb,
    const float* __restrict__ lw, const float* __restrict__ lbias,
    float* __restrict__ headW, float* __restrict__ headAux) {
  int t = threadIdx.x;
  float s = 0.f, acb = 0.f;
  for (int i = t; i < HDIM; i += 256) {
    float wp = lw[i] * lg[i];
    headW[i] = wp;
    s += wp;
    acb += lb[i] * lw[i];
  }
#pragma unroll
  for (int off = 1; off < 64; off <<= 1) { s += __shfl_xor(s, off); acb += __shfl_xor(acb, off); }
  __shared__ float rs[4], rb[4];
  int l = t & 63, w = t >> 6;
  if (l == 0) { rs[w] = s; rb[w] = acb; }
  __syncthreads();
  if (t == 0) {
    headAux[0] = rs[0] + rs[1] + rs[2] + rs[3];
    headAux[1] = lbias[0] + rb[0] + rb[1] + rb[2] + rb[3];
  }
}

// ---------------- stem weight pad+cast, PRE-SWIZZLED storage ----------------
__global__ __launch_bounds__(256) void fold_stem(const float* __restrict__ stw,
                                                 _Float16* __restrict__ Wst) {
  int idx = blockIdx.x * 256 + threadIdx.x;   // 1024*64
  int o = idx >> 6, j = idx & 63;
  int i = (((j >> 3) ^ (o & 7)) << 3) + (j & 7);
  Wst[idx] = (i < 26) ? (_Float16)stw[o * 26 + i] : (_Float16)0.f;
}

// ---------------- fused stem: LN(26) in-block + GEMM K=64 + bias/relu + stats ----------------
__global__ __launch_bounds__(256) void stem_gemm(
    const float* __restrict__ x, const float* __restrict__ stg, const float* __restrict__ stb,
    const _Float16* __restrict__ Wst, const float* __restrict__ stbias,
    _Float16* __restrict__ hout, float* __restrict__ stats_out, int rowBase) {
  __shared__ float xin[128 * 26];
  __shared__ _Float16 As[128 * 64];
  __shared__ _Float16 Bs[128 * 64];
  const int t = threadIdx.x;
  const int l = t & 63;
  const int w = t >> 6;
  const int wm = w >> 1, wn = w & 1;
  const int brow = blockIdx.x * 128;
  const int bcol = blockIdx.y * 128;

  // stage B (async, lands swizzled because Wst storage is pre-swizzled)
  const _Float16* gb = Wst + (size_t)(bcol + (t >> 3)) * 64 + (t & 7) * 8;
  char* lB = (char*)Bs + (size_t)w * 1024;
#pragma unroll
  for (int q = 0; q < 4; ++q) gload16(gb + (size_t)q * 32 * 64, lB + q * 4096);

  // raw x rows -> LDS (coalesced)
  const float* src = x + ((size_t)rowBase + brow) * 26;
  for (int i = t; i < 128 * 26; i += 256) xin[i] = src[i];
  __syncthreads();

  // LN per row (threads 0..127), write A-tile swizzled: chunk c stored at c^(row&7)
  if (t < 128) {
    float m = 0.f;
#pragma unroll
    for (int i = 0; i < 26; ++i) m += xin[t * 26 + i];
    m *= (1.f / 26.f);
    float v = 0.f;
#pragma unroll
    for (int i = 0; i < 26; ++i) { float d = xin[t * 26 + i] - m; v += d * d; }
    float rstd = rsqrtf(v * (1.f / 26.f) + EPSLN);
    _Float16 tmp[32];
#pragma unroll
    for (int i = 0; i < 26; ++i)
      tmp[i] = (_Float16)((xin[t * 26 + i] - m) * rstd * stg[i] + stb[i]);
#pragma unroll
    for (int i = 26; i < 32; ++i) tmp[i] = (_Float16)0.f;
    char* arow = (char*)As + t * 128;
#pragma unroll
    for (int c = 0; c < 4; ++c) {   // chunks 0..3 hold cols 0..31; 4..7 are zero
      f16x8 vv;
#pragma unroll
      for (int j = 0; j < 8; ++j) vv[j] = tmp[c * 8 + j];
      *(f16x8*)(arow + ((c ^ (t & 7)) << 4)) = vv;
    }
    f16x8 vz = (f16x8)(_Float16)0.f;
#pragma unroll
    for (int c = 4; c < 8; ++c) *(f16x8*)(arow + ((c ^ (t & 7)) << 4)) = vz;
  }
  __syncthreads();  // drains vmcnt (B staged) + lgkm (A written)

  f32x4 acc[4][4];
#pragma unroll
  for (int i = 0; i < 4; ++i)
#pragma unroll
    for (int j = 0; j < 4; ++j) acc[i][j] = (f32x4){0.f, 0.f, 0.f, 0.f};

#pragma unroll
  for (int ks = 0; ks < 2; ++ks) {
    const int cx = ((ks * 4 + (l >> 4)) ^ (l & 7)) << 4;
    f16x8 af[4], bfr[4];
#pragma unroll
    for (int m = 0; m < 4; ++m)
      af[m] = *(const f16x8*)((const char*)As + (wm * 64 + m * 16 + (l & 15)) * 128 + cx);
#pragma unroll
    for (int n = 0; n < 4; ++n)
      bfr[n] = *(const f16x8*)((const char*)Bs + (wn * 64 + n * 16 + (l & 15)) * 128 + cx);
#pragma unroll
    for (int m = 0; m < 4; ++m)
#pragma unroll
      for (int n = 0; n < 4; ++n)
        acc[m][n] = __builtin_amdgcn_mfma_f32_16x16x32_f16(af[m], bfr[n], acc[m][n], 0, 0, 0);
  }

  __syncthreads();               // done with xin; reuse as stats scratch
  float* sred = (float*)xin;     // 128 rows x {sum,sumsq}
  if (t < 256) sred[t] = 0.f;
  __syncthreads();

  float Bf[4];
#pragma unroll
  for (int n = 0; n < 4; ++n) Bf[n] = stbias[bcol + wn * 64 + n * 16 + (l & 15)];
#pragma unroll
  for (int m = 0; m < 4; ++m) {
#pragma unroll
    for (int rg = 0; rg < 4; ++rg) {
      int rloc = wm * 64 + m * 16 + (l >> 4) * 4 + rg;
      int lrow = brow + rloc;
      float ps = 0.f, psq = 0.f;
#pragma unroll
      for (int n = 0; n < 4; ++n) {
        int col = bcol + wn * 64 + n * 16 + (l & 15);
        float vv = fmaxf(acc[m][n][rg] + Bf[n], 0.f);
        hout[(size_t)lrow * HDIM + col] = (_Float16)vv;
        ps += vv; psq += vv * vv;
      }
#pragma unroll
      for (int off = 1; off < 16; off <<= 1) {
        ps += __shfl_xor(ps, off);
        psq += __shfl_xor(psq, off);
      }
      if ((l & 15) == 0) {
        atomicAdd(&sred[rloc * 2 + 0], ps);
        atomicAdd(&sred[rloc * 2 + 1], psq);
      }
    }
  }
  __syncthreads();
  if (t < 256) atomicAdd(&stats_out[(size_t)(brow + (t >> 1)) * 2 + (t & 1)], sred[t]);
}

// ---------------- per-layer fused GEMM, 128x256 tile, 4 waves, B direct from L2 ----------------
// 256 thr = 4 waves (wn 0..3); per-wave 128x64 = acc[8][4]; BK=32, 32 MFMA/wave/tile.
// A: LDS 2-buf (2x8KB), staged via gload_lds (2/tile), R5-verified swizzle chunk^=(row>>1)&3.
// B: direct global->reg, 4 x global_load_dwordx4 per tile per wave (lane l holds
//    B[col = wn*64 + n*16 + (l&15), k = kt*32 + (l>>4)*8 + 0..7] -- the exact MFMA B-frag).
// FIFO per tile: issue [A(kt+1) x2, B(kt+1) x4]; pre-MFMA s_waitcnt vmcnt(6) (B(kt) landed);
// boundary vmcnt(4)+s_barrier (A(kt+1) landed; B(kt+1) rides through). vmcnt(0) only at tail.
__global__ __launch_bounds__(256, 2) void layer_gemm(
    const _Float16* __restrict__ hin, const float* __restrict__ stats_in,
    const _Float16* __restrict__ W, const float* __restrict__ bfold,
    const float* __restrict__ Sfold, _Float16* __restrict__ hout,
    float* __restrict__ stats_out) {
  __shared__ __align__(128) char smem[2 * 8192];  // A only: buf p at p*8192
  const int t = threadIdx.x;
  const int l = t & 63;
  const int w = t >> 6;
  const int wn = w;                    // 4 waves across N
  int bid = blockIdx.x;
  {  // XCD chunk swizzle: contiguous bid range per XCD (A-panel groups share one L2)
    int nb = gridDim.x;
    if ((nb & 7) == 0) { int cpx = nb >> 3; bid = (bid & 7) * cpx + (bid >> 3); }
  }
  const int brow = (bid >> 2) * 128;   // consecutive bids share the A-panel
  const int bcol = (bid & 3) * 256;

  f32x4 acc[8][4];
#pragma unroll
  for (int i = 0; i < 8; ++i)
#pragma unroll
    for (int j = 0; j < 4; ++j) acc[i][j] = (f32x4){0.f, 0.f, 0.f, 0.f};

  // A staging: thread t -> row t>>2, chunk t&3 (64B rows), source chunk pre-swizzled
  const int cswz = (t & 3) ^ ((t >> 3) & 3);
  const _Float16* gA = hin + (size_t)(brow + (t >> 2)) * HDIM + cswz * 8;
  const int dstw = w << 10;  // wave-uniform LDS dest offset (lane adds l*16)

  auto stageA = [&](int kt) {
    char* dA = smem + (kt & 1) * 8192 + dstw;
    const _Float16* sA = gA + kt * 32;
    gload16(sA, dA);                             // rows 0-63
    gload16(sA + (size_t)64 * HDIM, dA + 4096);  // rows 64-127
  };

  // B per-lane pointer: col = bcol + wn*64 + n*16 + (l&15); k-chunk (l>>4)*8
  const _Float16* gBf = W + (size_t)(bcol + wn * 64 + (l & 15)) * HDIM + (l >> 4) * 8;

  // ds_read: row rl at rl*64, chunk (l>>4) ^ ((rl>>1)&3)
  const int rl = l & 15;
  const int cx = (((l >> 4) ^ ((rl >> 1) & 3)) << 4);
  const int arow0 = rl * 64 + cx;  // + m*1024

  f16x8 bf0[4], bf1[4];

#define LOADB(kt, dst)                                                        \
  do {                                                                        \
    _Pragma("unroll") for (int n = 0; n < 4; ++n)                             \
        dst[n] = *(const f16x8*)(gBf + (size_t)n * 16 * HDIM + (kt) * 32);    \
  } while (0)
#define DS_AF(bufkt)                                                          \
  do {                                                                        \
    const char* bc = smem + ((bufkt) & 1) * 8192;                             \
    _Pragma("unroll") for (int m = 0; m < 8; ++m)                             \
        af[m] = *(const f16x8*)(bc + arow0 + m * 1024);                       \
  } while (0)
#define MFMA32(src)                                                           \
  do {                                                                        \
    __builtin_amdgcn_s_setprio(1);                                            \
    _Pragma("unroll") for (int m = 0; m < 8; ++m)                             \
        _Pragma("unroll") for (int n = 0; n < 4; ++n)                         \
            acc[m][n] = __builtin_amdgcn_mfma_f32_16x16x32_f16(af[m], src[n], \
                                                               acc[m][n], 0, 0, 0); \
    __builtin_amdgcn_s_setprio(0);                                            \
  } while (0)
#define WAIT_PRE(N)                                                           \
  do {                                                                        \
    asm volatile("s_waitcnt vmcnt(" #N ") lgkmcnt(0)" ::: "memory");          \
    __builtin_amdgcn_sched_barrier(0);                                        \
  } while (0)
#define BOUNDARY()                                                            \
  do {                                                                        \
    __builtin_amdgcn_sched_barrier(0);                                        \
    asm volatile("s_waitcnt vmcnt(4)" ::: "memory");                          \
    __builtin_amdgcn_s_barrier();                                             \
    __builtin_amdgcn_sched_barrier(0);                                        \
  } while (0)

  f16x8 af[8];

  // prologue: A(0), B(0)
  stageA(0);
  LOADB(0, bf0);
  asm volatile("s_waitcnt vmcnt(4)" ::: "memory");  // A(0) landed (B(0) x4 in flight)
  __builtin_amdgcn_s_barrier();
  __builtin_amdgcn_sched_barrier(0);

#pragma unroll 1
  for (int kt2 = 0; kt2 < 15; ++kt2) {
    const int kt = kt2 * 2;
    // even tile kt: cur bf0, issue kt+1 -> bf1
    stageA(kt + 1);
    LOADB(kt + 1, bf1);
    DS_AF(kt);
    WAIT_PRE(6);   // B(kt) landed; A(kt+1)+B(kt+1) = 6 in flight
    MFMA32(bf0);
    BOUNDARY();    // A(kt+1) landed; B(kt+1) rides through
    // odd tile kt+1: cur bf1, issue kt+2 -> bf0
    stageA(kt + 2);
    LOADB(kt + 2, bf0);
    DS_AF(kt + 1);
    WAIT_PRE(6);
    MFMA32(bf1);
    BOUNDARY();
  }
  // kt = 30: cur bf0, issue 31 -> bf1
  stageA(31);
  LOADB(31, bf1);
  DS_AF(30);
  WAIT_PRE(6);
  MFMA32(bf0);
  BOUNDARY();
  // kt = 31: tail, cur bf1, no issues
  DS_AF(31);
  WAIT_PRE(0);
  MFMA32(bf1);
  __syncthreads();  // full drain before LDS reuse

#undef LOADB
#undef DS_AF
#undef MFMA32
#undef WAIT_PRE
#undef BOUNDARY

  // ---- epilogue: LN-affine + relu + fp16 store; stats combined in LDS, then 1 atomic/row-val ----
  float* sred = (float*)smem;  // 128 rows x {sum, sumsq} = 256 floats
  sred[t] = 0.f;
  __syncthreads();

  float Sf[4], Bf2[4];
#pragma unroll
  for (int n = 0; n < 4; ++n) {
    int col = bcol + wn * 64 + n * 16 + rl;
    Sf[n] = Sfold[col];
    Bf2[n] = bfold[col];
  }
#pragma unroll
  for (int m = 0; m < 8; ++m) {
#pragma unroll
    for (int rg = 0; rg < 4; ++rg) {
      int rloc = m * 16 + (l >> 4) * 4 + rg;  // C/D: col=lane&15, row=(lane>>4)*4+reg
      int grow = brow + rloc;
      float sum = stats_in[(size_t)grow * 2 + 0];
      float sumsq = stats_in[(size_t)grow * 2 + 1];
      float mean = sum * (1.f / 1024.f);
      float rstd = rsqrtf(sumsq * (1.f / 1024.f) - mean * mean + EPSLN);
      float ps = 0.f, psq = 0.f;
#pragma unroll
      for (int n = 0; n < 4; ++n) {
        int col = bcol + wn * 64 + n * 16 + rl;
        float vv = rstd * (acc[m][n][rg] - mean * Sf[n]) + Bf2[n];
        vv = fmaxf(vv, 0.f);
        hout[(size_t)grow * HDIM + col] = (_Float16)vv;
        ps += vv; psq += vv * vv;
      }
#pragma unroll
      for (int off2 = 1; off2 < 16; off2 <<= 1) {
        ps += __shfl_xor(ps, off2);
        psq += __shfl_xor(psq, off2);
      }
      if (rl == 0) {
        atomicAdd(&sred[rloc * 2 + 0], ps);
        atomicAdd(&sred[rloc * 2 + 1], psq);
      }
    }
  }
  __syncthreads();
  atomicAdd(&stats_out[(size_t)(brow + (t >> 1)) * 2 + (t & 1)], sred[t]);
}

// ---------------- head: out = sigmoid(rstd*(h8@W'' - mean*S'') + b''), one wave per row ----------------
__global__ __launch_bounds__(512) void head_kernel(
    const _Float16* __restrict__ h8, const float* __restrict__ stats8,
    const float* __restrict__ headW, const float* __restrict__ headAux,
    float* __restrict__ out, int rowBase) {
  int t = threadIdx.x, l = t & 63, w = t >> 6;
  int lrow = blockIdx.x * 8 + w;
  const f16x8* hp = (const f16x8*)(h8 + (size_t)lrow * HDIM) + l * 2;
  f16x8 v0 = hp[0], v1 = hp[1];
  float acc = 0.f;
#pragma unroll
  for (int j = 0; j < 8; ++j) acc += (float)v0[j] * headW[l * 16 + j];
#pragma unroll
  for (int j = 0; j < 8; ++j) acc += (float)v1[j] * headW[l * 16 + 8 + j];
#pragma unroll
  for (int off = 1; off < 64; off <<= 1) acc += __shfl_xor(acc, off);
  if (l == 0) {
    float sum = stats8[lrow * 2 + 0], sumsq = stats8[lrow * 2 + 1];
    float mean = sum * (1.f / 1024.f);
    float rstd = rsqrtf(sumsq * (1.f / 1024.f) - mean * mean + EPSLN);
    float z = rstd * (acc - mean * headAux[0]) + headAux[1];
    out[rowBase + lrow] = 1.f / (1.f + expf(-z));
  }
}

extern "C" void kernel_launch(void* const* d_in, const int* in_sizes, int n_in,
                              void* d_out, int out_size, void* d_ws, size_t ws_size,
                              hipStream_t stream) {
  const float* x      = (const float*)d_in[0];
  const float* stg    = (const float*)d_in[1];
  const float* stb    = (const float*)d_in[2];
  const float* stw    = (const float*)d_in[3];
  const float* stbias = (const float*)d_in[4];
  const float* bg     = (const float*)d_in[5];
  const float* bb     = (const float*)d_in[6];
  const float* bw     = (const float*)d_in[7];
  const float* bbias  = (const float*)d_in[8];
  const float* lg     = (const float*)d_in[9];
  const float* lb     = (const float*)d_in[10];
  const float* lw     = (const float*)d_in[11];
  const float* lbias  = (const float*)d_in[12];
  float* out = (float*)d_out;
  const int B = 65536;
  const int L = 8;

  char* ws = (char*)d_ws;
  size_t off = 0;
  auto carve = [&](size_t bytes) -> char* {
    char* p = ws + off;
    off = (off + bytes + 255) & ~(size_t)255;
    return p;
  };
  _Float16* Wf   = (_Float16*)carve((size_t)L * HDIM * HDIM * 2);
  float* bfold   = (float*)carve((size_t)L * HDIM * 4);
  float* Sfold   = (float*)carve((size_t)L * HDIM * 4);
  float* headW   = (float*)carve((size_t)HDIM * 4);
  float* headAux = (float*)carve(256);
  _Float16* Wst  = (_Float16*)carve((size_t)HDIM * 64 * 2);
  size_t fixed = off;

  // pick largest batch chunk R (power of 2, >=256) whose buffers fit in ws
  int R = B;
  while (R > 256) {
    size_t need = fixed + 2 * ((size_t)R * HDIM * 2 + 256) + ((size_t)9 * R * 2 * 4 + 256);
    if (need <= ws_size) break;
    R >>= 1;
  }
  _Float16* hA = (_Float16*)carve((size_t)R * HDIM * 2);
  _Float16* hB = (_Float16*)carve((size_t)R * HDIM * 2);
  float* stats = (float*)carve((size_t)9 * R * 2 * 4);  // 9 slots: h0..h8 (sum,sumsq)

  fold_blk<<<L * HDIM, 256, 0, stream>>>(bg, bb, bw, bbias, Wf, bfold, Sfold);
  fold_head<<<1, 256, 0, stream>>>(lg, lb, lw, lbias, headW, headAux);
  fold_stem<<<HDIM * 64 / 256, 256, 0, stream>>>(stw, Wst);

  const int nstats = 9 * R * 2;
  for (int c = 0; c < B / R; ++c) {
    int rowBase = c * R;
    zero_f32<<<(nstats + 255) / 256, 256, 0, stream>>>(stats, nstats);
    {
      dim3 grid(R / 128, 8);
      stem_gemm<<<grid, 256, 0, stream>>>(x, stg, stb, Wst, stbias, hA, stats, rowBase);
    }
    _Float16* cur = hA;
    _Float16* nxt = hB;
    for (int lyr = 0; lyr < L; ++lyr) {
      int nb = (R / 128) * 4;
      layer_gemm<<<nb, 256, 0, stream>>>(
          cur, stats + (size_t)lyr * R * 2, Wf + (size_t)lyr * HDIM * HDIM,
          bfold + lyr * HDIM, Sfold + lyr * HDIM, nxt, stats + (size_t)(lyr + 1) * R * 2);
      _Float16* tmp = cur; cur = nxt; nxt = tmp;
    }
    head_kernel<<<R / 8, 512, 0, stream>>>(cur, stats + (size_t)8 * R * 2, headW, headAux, out, rowBase);
  }
}

// Round 10
// 1410.096 us; speedup vs baseline: 1.2592x; 1.2592x over previous
//
#include <hip/hip_runtime.h>
#include <hip/hip_bf16.h>
#include <stdint.h>

// DeepFakeDetectionModel: stem LN(26)->Linear(26->1024)->ReLU, 8x [LN->Linear(1024->1024)->ReLU],
// head LN->Linear(1024->1)->sigmoid.  B=65536.
//
// LN folded into weights; GEMMs on RAW fp16 activations; LN affine in epilogue via per-row stats.
// R2-R7: swizzles + schedules plateau ~755 TF. Cycle model: LDS traffic (B reads + staging) =
//        2031 cyc per BK-64 per CU vs 2483 MFMA cyc -> pipes don't overlap enough.
// R8: B direct L2->reg failed on coalescing (16 scattered 64B segments per load).
// R9: B pre-packed FRAGMENT-MAJOR (Wfrag[n16][kc][lane][8]): one global_load_dwordx4 = one
//     MFMA B-frag AND a contiguous 1KB wave read from L2. B never touches LDS (traffic
//     260->160KB per BK-64). Counted FIFO: pre-MFMA vmcnt(6) drains B(kt) only; boundary
//     vmcnt(4)+barrier; vmcnt(0) only at tail. R7 geometry (256thr, 128x256, BK=32, 2 blk/CU).

typedef __attribute__((ext_vector_type(8))) _Float16 f16x8;
typedef __attribute__((ext_vector_type(4))) float f32x4;

#define EPSLN 1e-5f
#define HDIM 1024

__device__ __forceinline__ void gload16(const void* g, void* l) {
  __builtin_amdgcn_global_load_lds(
      (const __attribute__((address_space(1))) unsigned int*)g,
      (__attribute__((address_space(3))) unsigned int*)l, 16, 0, 0);
}

// ---------------- zero stats ----------------
__global__ __launch_bounds__(256) void zero_f32(float* __restrict__ p, int n) {
  int i = blockIdx.x * 256 + threadIdx.x;
  if (i < n) p[i] = 0.f;
}

// ---------------- fold block scalars: S'=sum(fp16(gamma*W)), b'=b+beta@W ----------------
__global__ __launch_bounds__(256) void fold_blk(
    const float* __restrict__ bg, const float* __restrict__ bb,
    const float* __restrict__ bw, const float* __restrict__ bbias,
    float* __restrict__ bfold, float* __restrict__ Sfold) {
  int lo = blockIdx.x;            // layer*1024 + o
  int layer = lo >> 10;
  const float* wrow = bw + (size_t)lo * HDIM;
  const float* g = bg + (size_t)layer * HDIM;
  const float* be = bb + (size_t)layer * HDIM;
  int t = threadIdx.x;
  float s = 0.f, acb = 0.f;
  for (int i = t; i < HDIM; i += 256) {
    float wv = wrow[i];
    _Float16 wp = (_Float16)(wv * g[i]);   // same rounding as fold_pack -> S' consistent
    s += (float)wp;
    acb += be[i] * wv;
  }
#pragma unroll
  for (int off = 1; off < 64; off <<= 1) { s += __shfl_xor(s, off); acb += __shfl_xor(acb, off); }
  __shared__ float rs[4], rb[4];
  int l = t & 63, w = t >> 6;
  if (l == 0) { rs[w] = s; rb[w] = acb; }
  __syncthreads();
  if (t == 0) {
    Sfold[lo] = rs[0] + rs[1] + rs[2] + rs[3];
    bfold[lo] = bbias[lo] + rb[0] + rb[1] + rb[2] + rb[3];
  }
}

// ---------------- pack W' fragment-major: Wfrag[lay][n16][kc][lane][8] ----------------
// lane l of frag (n16,kc) holds W'[col = n16*16 + (l&15), k = kc*32 + (l>>4)*8 + j].
// One wave global_load_dwordx4 at offset ((n16*32+kc)*64 + l)*8 = contiguous 1KB = one B-frag.
__global__ __launch_bounds__(256) void fold_pack(
    const float* __restrict__ bg, const float* __restrict__ bw,
    _Float16* __restrict__ Wfrag) {
  size_t tid = (size_t)blockIdx.x * 256 + threadIdx.x;  // over L*131072 octets
  int lay = (int)(tid >> 17);
  int oct = (int)(tid & 131071);
  int frag = oct >> 6, lane = oct & 63;
  int n16 = frag >> 5, kc = frag & 31;
  int o = n16 * 16 + (lane & 15);
  int ibase = kc * 32 + ((lane >> 4) << 3);
  const float* wrow = bw + ((size_t)lay << 20) + (size_t)o * HDIM + ibase;
  const float* g = bg + (size_t)lay * HDIM + ibase;
  f16x8 v;
#pragma unroll
  for (int j = 0; j < 8; ++j) v[j] = (_Float16)(wrow[j] * g[j]);
  *(f16x8*)(Wfrag + tid * 8) = v;
}

// ---------------- fold head ----------------
__global__ __launch_bounds__(256) void fold_head(
    const float* __restrict__ lg, const float* __restrict__ lb,
    const float* __restrict__ lw, const float* __restrict__ lbias,
    float* __restrict__ headW, float* __restrict__ headAux) {
  int t = threadIdx.x;
  float s = 0.f, acb = 0.f;
  for (int i = t; i < HDIM; i += 256) {
    float wp = lw[i] * lg[i];
    headW[i] = wp;
    s += wp;
    acb += lb[i] * lw[i];
  }
#pragma unroll
  for (int off = 1; off < 64; off <<= 1) { s += __shfl_xor(s, off); acb += __shfl_xor(acb, off); }
  __shared__ float rs[4], rb[4];
  int l = t & 63, w = t >> 6;
  if (l == 0) { rs[w] = s; rb[w] = acb; }
  __syncthreads();
  if (t == 0) {
    headAux[0] = rs[0] + rs[1] + rs[2] + rs[3];
    headAux[1] = lbias[0] + rb[0] + rb[1] + rb[2] + rb[3];
  }
}

// ---------------- stem weight pad+cast, PRE-SWIZZLED storage ----------------
__global__ __launch_bounds__(256) void fold_stem(const float* __restrict__ stw,
                                                 _Float16* __restrict__ Wst) {
  int idx = blockIdx.x * 256 + threadIdx.x;   // 1024*64
  int o = idx >> 6, j = idx & 63;
  int i = (((j >> 3) ^ (o & 7)) << 3) + (j & 7);
  Wst[idx] = (i < 26) ? (_Float16)stw[o * 26 + i] : (_Float16)0.f;
}

// ---------------- fused stem: LN(26) in-block + GEMM K=64 + bias/relu + stats ----------------
__global__ __launch_bounds__(256) void stem_gemm(
    const float* __restrict__ x, const float* __restrict__ stg, const float* __restrict__ stb,
    const _Float16* __restrict__ Wst, const float* __restrict__ stbias,
    _Float16* __restrict__ hout, float* __restrict__ stats_out, int rowBase) {
  __shared__ float xin[128 * 26];
  __shared__ _Float16 As[128 * 64];
  __shared__ _Float16 Bs[128 * 64];
  const int t = threadIdx.x;
  const int l = t & 63;
  const int w = t >> 6;
  const int wm = w >> 1, wn = w & 1;
  const int brow = blockIdx.x * 128;
  const int bcol = blockIdx.y * 128;

  // stage B (async, lands swizzled because Wst storage is pre-swizzled)
  const _Float16* gb = Wst + (size_t)(bcol + (t >> 3)) * 64 + (t & 7) * 8;
  char* lB = (char*)Bs + (size_t)w * 1024;
#pragma unroll
  for (int q = 0; q < 4; ++q) gload16(gb + (size_t)q * 32 * 64, lB + q * 4096);

  // raw x rows -> LDS (coalesced)
  const float* src = x + ((size_t)rowBase + brow) * 26;
  for (int i = t; i < 128 * 26; i += 256) xin[i] = src[i];
  __syncthreads();

  // LN per row (threads 0..127), write A-tile swizzled: chunk c stored at c^(row&7)
  if (t < 128) {
    float m = 0.f;
#pragma unroll
    for (int i = 0; i < 26; ++i) m += xin[t * 26 + i];
    m *= (1.f / 26.f);
    float v = 0.f;
#pragma unroll
    for (int i = 0; i < 26; ++i) { float d = xin[t * 26 + i] - m; v += d * d; }
    float rstd = rsqrtf(v * (1.f / 26.f) + EPSLN);
    _Float16 tmp[32];
#pragma unroll
    for (int i = 0; i < 26; ++i)
      tmp[i] = (_Float16)((xin[t * 26 + i] - m) * rstd * stg[i] + stb[i]);
#pragma unroll
    for (int i = 26; i < 32; ++i) tmp[i] = (_Float16)0.f;
    char* arow = (char*)As + t * 128;
#pragma unroll
    for (int c = 0; c < 4; ++c) {   // chunks 0..3 hold cols 0..31; 4..7 are zero
      f16x8 vv;
#pragma unroll
      for (int j = 0; j < 8; ++j) vv[j] = tmp[c * 8 + j];
      *(f16x8*)(arow + ((c ^ (t & 7)) << 4)) = vv;
    }
    f16x8 vz = (f16x8)(_Float16)0.f;
#pragma unroll
    for (int c = 4; c < 8; ++c) *(f16x8*)(arow + ((c ^ (t & 7)) << 4)) = vz;
  }
  __syncthreads();  // drains vmcnt (B staged) + lgkm (A written)

  f32x4 acc[4][4];
#pragma unroll
  for (int i = 0; i < 4; ++i)
#pragma unroll
    for (int j = 0; j < 4; ++j) acc[i][j] = (f32x4){0.f, 0.f, 0.f, 0.f};

#pragma unroll
  for (int ks = 0; ks < 2; ++ks) {
    const int cx = ((ks * 4 + (l >> 4)) ^ (l & 7)) << 4;
    f16x8 af[4], bfr[4];
#pragma unroll
    for (int m = 0; m < 4; ++m)
      af[m] = *(const f16x8*)((const char*)As + (wm * 64 + m * 16 + (l & 15)) * 128 + cx);
#pragma unroll
    for (int n = 0; n < 4; ++n)
      bfr[n] = *(const f16x8*)((const char*)Bs + (wn * 64 + n * 16 + (l & 15)) * 128 + cx);
#pragma unroll
    for (int m = 0; m < 4; ++m)
#pragma unroll
      for (int n = 0; n < 4; ++n)
        acc[m][n] = __builtin_amdgcn_mfma_f32_16x16x32_f16(af[m], bfr[n], acc[m][n], 0, 0, 0);
  }

  __syncthreads();               // done with xin; reuse as stats scratch
  float* sred = (float*)xin;     // 128 rows x {sum,sumsq}
  if (t < 256) sred[t] = 0.f;
  __syncthreads();

  float Bf[4];
#pragma unroll
  for (int n = 0; n < 4; ++n) Bf[n] = stbias[bcol + wn * 64 + n * 16 + (l & 15)];
#pragma unroll
  for (int m = 0; m < 4; ++m) {
#pragma unroll
    for (int rg = 0; rg < 4; ++rg) {
      int rloc = wm * 64 + m * 16 + (l >> 4) * 4 + rg;
      int lrow = brow + rloc;
      float ps = 0.f, psq = 0.f;
#pragma unroll
      for (int n = 0; n < 4; ++n) {
        int col = bcol + wn * 64 + n * 16 + (l & 15);
        float vv = fmaxf(acc[m][n][rg] + Bf[n], 0.f);
        hout[(size_t)lrow * HDIM + col] = (_Float16)vv;
        ps += vv; psq += vv * vv;
      }
#pragma unroll
      for (int off = 1; off < 16; off <<= 1) {
        ps += __shfl_xor(ps, off);
        psq += __shfl_xor(psq, off);
      }
      if ((l & 15) == 0) {
        atomicAdd(&sred[rloc * 2 + 0], ps);
        atomicAdd(&sred[rloc * 2 + 1], psq);
      }
    }
  }
  __syncthreads();
  if (t < 256) atomicAdd(&stats_out[(size_t)(brow + (t >> 1)) * 2 + (t & 1)], sred[t]);
}

// ---------------- per-layer fused GEMM, 128x256 tile, B-frags direct from L2 ----------------
// 256 thr = 4 waves (wn 0..3); per-wave 128x64 = acc[8][4]; BK=32, 32 MFMA/wave/tile.
// A: LDS 2-buf (2x8KB), gload_lds x2/tile, R5 swizzle chunk^=(row>>1)&3 (conflicts=0).
// B: Wfrag fragment-major -> 4 coalesced global_load_dwordx4/tile/wave, no LDS.
// FIFO per tile: issue [A(kt+1) x2 lds, B(kt+1) x4 reg]; pre-MFMA vmcnt(6)+lgkmcnt(0)
// (drains B(kt) only); boundary vmcnt(4)+s_barrier (A(kt+1) landed, B(kt+1) in flight).
__global__ __launch_bounds__(256, 2) void layer_gemm(
    const _Float16* __restrict__ hin, const float* __restrict__ stats_in,
    const _Float16* __restrict__ Wfrag, const float* __restrict__ bfold,
    const float* __restrict__ Sfold, _Float16* __restrict__ hout,
    float* __restrict__ stats_out) {
  __shared__ __align__(128) char smem[2 * 8192];  // A only
  const int t = threadIdx.x;
  const int l = t & 63;
  const int w = t >> 6;
  const int wn = w;
  int bid = blockIdx.x;
  {  // XCD chunk swizzle
    int nb = gridDim.x;
    if ((nb & 7) == 0) { int cpx = nb >> 3; bid = (bid & 7) * cpx + (bid >> 3); }
  }
  const int brow = (bid >> 2) * 128;   // consecutive bids share the A-panel
  const int bcol = (bid & 3) * 256;

  f32x4 acc[8][4];
#pragma unroll
  for (int i = 0; i < 8; ++i)
#pragma unroll
    for (int j = 0; j < 4; ++j) acc[i][j] = (f32x4){0.f, 0.f, 0.f, 0.f};

  // A staging: thread t -> row t>>2, chunk t&3 (64B rows), source chunk pre-swizzled
  const int cswz = (t & 3) ^ ((t >> 3) & 3);
  const _Float16* gA = hin + (size_t)(brow + (t >> 2)) * HDIM + cswz * 8;
  const int dstw = w << 10;

  auto stageA = [&](int kt) {
    char* dA = smem + (kt & 1) * 8192 + dstw;
    const _Float16* sA = gA + kt * 32;
    gload16(sA, dA);                             // rows 0-63
    gload16(sA + (size_t)64 * HDIM, dA + 4096);  // rows 64-127
  };

  // B frag base: frag (n16_0 + n, kt) at ((n16*32+kt)*64 + l)*8 elements
  const _Float16* gBf = Wfrag + ((size_t)((bcol >> 4) + wn * 4) * 2048 + l) * 8;

  const int rl = l & 15;
  const int cx = (((l >> 4) ^ ((rl >> 1) & 3)) << 4);
  const int arow0 = rl * 64 + cx;  // + m*1024

  f16x8 af[8], bf0[4], bf1[4];

#define LOADB(kt, dst)                                                         \
  do {                                                                         \
    _Pragma("unroll") for (int n = 0; n < 4; ++n)                              \
        dst[n] = *(const f16x8*)(gBf + (size_t)n * 16384 + (kt) * 512);        \
  } while (0)
#define DS_AF(kt)                                                              \
  do {                                                                         \
    const char* bc = smem + ((kt) & 1) * 8192;                                 \
    _Pragma("unroll") for (int m = 0; m < 8; ++m)                              \
        af[m] = *(const f16x8*)(bc + arow0 + m * 1024);                        \
  } while (0)
#define MFMA32(src)                                                            \
  do {                                                                         \
    __builtin_amdgcn_s_setprio(1);                                             \
    _Pragma("unroll") for (int m = 0; m < 8; ++m)                              \
        _Pragma("unroll") for (int n = 0; n < 4; ++n)                          \
            acc[m][n] = __builtin_amdgcn_mfma_f32_16x16x32_f16(af[m], src[n],  \
                                                               acc[m][n], 0, 0, 0); \
    __builtin_amdgcn_s_setprio(0);                                             \
  } while (0)
#define WAIT_PRE(N)                                                            \
  do {                                                                         \
    asm volatile("s_waitcnt vmcnt(" #N ") lgkmcnt(0)" ::: "memory");           \
    __builtin_amdgcn_sched_barrier(0);                                         \
  } while (0)
#define BOUNDARY()                                                             \
  do {                                                                         \
    __builtin_amdgcn_sched_barrier(0);                                         \
    asm volatile("s_waitcnt vmcnt(4)" ::: "memory");                           \
    __builtin_amdgcn_s_barrier();                                              \
    __builtin_amdgcn_sched_barrier(0);                                         \
  } while (0)

  // prologue: A(0)->LDS, B(0)->bf0
  stageA(0);
  LOADB(0, bf0);
  asm volatile("s_waitcnt vmcnt(4)" ::: "memory");  // A(0) landed; B(0) x4 in flight
  __builtin_amdgcn_s_barrier();
  __builtin_amdgcn_sched_barrier(0);

#pragma unroll 1
  for (int kt2 = 0; kt2 < 15; ++kt2) {
    const int kt = kt2 * 2;
    stageA(kt + 1);
    LOADB(kt + 1, bf1);
    DS_AF(kt);
    WAIT_PRE(6);   // drains B(kt); A(kt+1)+B(kt+1)=6 stay in flight
    MFMA32(bf0);
    BOUNDARY();
    stageA(kt + 2);
    LOADB(kt + 2, bf0);
    DS_AF(kt + 1);
    WAIT_PRE(6);
    MFMA32(bf1);
    BOUNDARY();
  }
  // kt = 30: issue 31
  stageA(31);
  LOADB(31, bf1);
  DS_AF(30);
  WAIT_PRE(6);
  MFMA32(bf0);
  BOUNDARY();
  // kt = 31 tail
  DS_AF(31);
  WAIT_PRE(0);
  MFMA32(bf1);
  __syncthreads();

#undef LOADB
#undef DS_AF
#undef MFMA32
#undef WAIT_PRE
#undef BOUNDARY

  // ---- epilogue: LN-affine + relu + fp16 store; stats combined in LDS ----
  float* sred = (float*)smem;  // 128 rows x {sum, sumsq} = 256 floats
  sred[t] = 0.f;
  __syncthreads();

  float Sf[4], Bf2[4];
#pragma unroll
  for (int n = 0; n < 4; ++n) {
    int col = bcol + wn * 64 + n * 16 + rl;
    Sf[n] = Sfold[col];
    Bf2[n] = bfold[col];
  }
#pragma unroll
  for (int m = 0; m < 8; ++m) {
#pragma unroll
    for (int rg = 0; rg < 4; ++rg) {
      int rloc = m * 16 + (l >> 4) * 4 + rg;  // C/D: col=lane&15, row=(lane>>4)*4+reg
      int grow = brow + rloc;
      float sum = stats_in[(size_t)grow * 2 + 0];
      float sumsq = stats_in[(size_t)grow * 2 + 1];
      float mean = sum * (1.f / 1024.f);
      float rstd = rsqrtf(sumsq * (1.f / 1024.f) - mean * mean + EPSLN);
      float ps = 0.f, psq = 0.f;
#pragma unroll
      for (int n = 0; n < 4; ++n) {
        int col = bcol + wn * 64 + n * 16 + rl;
        float vv = rstd * (acc[m][n][rg] - mean * Sf[n]) + Bf2[n];
        vv = fmaxf(vv, 0.f);
        hout[(size_t)grow * HDIM + col] = (_Float16)vv;
        ps += vv; psq += vv * vv;
      }
#pragma unroll
      for (int off2 = 1; off2 < 16; off2 <<= 1) {
        ps += __shfl_xor(ps, off2);
        psq += __shfl_xor(psq, off2);
      }
      if (rl == 0) {
        atomicAdd(&sred[rloc * 2 + 0], ps);
        atomicAdd(&sred[rloc * 2 + 1], psq);
      }
    }
  }
  __syncthreads();
  atomicAdd(&stats_out[(size_t)(brow + (t >> 1)) * 2 + (t & 1)], sred[t]);
}

// ---------------- head ----------------
__global__ __launch_bounds__(512) void head_kernel(
    const _Float16* __restrict__ h8, const float* __restrict__ stats8,
    const float* __restrict__ headW, const float* __restrict__ headAux,
    float* __restrict__ out, int rowBase) {
  int t = threadIdx.x, l = t & 63, w = t >> 6;
  int lrow = blockIdx.x * 8 + w;
  const f16x8* hp = (const f16x8*)(h8 + (size_t)lrow * HDIM) + l * 2;
  f16x8 v0 = hp[0], v1 = hp[1];
  float acc = 0.f;
#pragma unroll
  for (int j = 0; j < 8; ++j) acc += (float)v0[j] * headW[l * 16 + j];
#pragma unroll
  for (int j = 0; j < 8; ++j) acc += (float)v1[j] * headW[l * 16 + 8 + j];
#pragma unroll
  for (int off = 1; off < 64; off <<= 1) acc += __shfl_xor(acc, off);
  if (l == 0) {
    float sum = stats8[lrow * 2 + 0], sumsq = stats8[lrow * 2 + 1];
    float mean = sum * (1.f / 1024.f);
    float rstd = rsqrtf(sumsq * (1.f / 1024.f) - mean * mean + EPSLN);
    float z = rstd * (acc - mean * headAux[0]) + headAux[1];
    out[rowBase + lrow] = 1.f / (1.f + expf(-z));
  }
}

extern "C" void kernel_launch(void* const* d_in, const int* in_sizes, int n_in,
                              void* d_out, int out_size, void* d_ws, size_t ws_size,
                              hipStream_t stream) {
  const float* x      = (const float*)d_in[0];
  const float* stg    = (const float*)d_in[1];
  const float* stb    = (const float*)d_in[2];
  const float* stw    = (const float*)d_in[3];
  const float* stbias = (const float*)d_in[4];
  const float* bg     = (const float*)d_in[5];
  const float* bb     = (const float*)d_in[6];
  const float* bw     = (const float*)d_in[7];
  const float* bbias  = (const float*)d_in[8];
  const float* lg     = (const float*)d_in[9];
  const float* lb     = (const float*)d_in[10];
  const float* lw     = (const float*)d_in[11];
  const float* lbias  = (const float*)d_in[12];
  float* out = (float*)d_out;
  const int B = 65536;
  const int L = 8;

  char* ws = (char*)d_ws;
  size_t off = 0;
  auto carve = [&](size_t bytes) -> char* {
    char* p = ws + off;
    off = (off + bytes + 255) & ~(size_t)255;
    return p;
  };
  _Float16* Wfrag = (_Float16*)carve((size_t)L * HDIM * HDIM * 2);
  float* bfold   = (float*)carve((size_t)L * HDIM * 4);
  float* Sfold   = (float*)carve((size_t)L * HDIM * 4);
  float* headW   = (float*)carve((size_t)HDIM * 4);
  float* headAux = (float*)carve(256);
  _Float16* Wst  = (_Float16*)carve((size_t)HDIM * 64 * 2);
  size_t fixed = off;

  // pick largest batch chunk R (power of 2, >=256) whose buffers fit in ws
  int R = B;
  while (R > 256) {
    size_t need = fixed + 2 * ((size_t)R * HDIM * 2 + 256) + ((size_t)9 * R * 2 * 4 + 256);
    if (need <= ws_size) break;
    R >>= 1;
  }
  _Float16* hA = (_Float16*)carve((size_t)R * HDIM * 2);
  _Float16* hB = (_Float16*)carve((size_t)R * HDIM * 2);
  float* stats = (float*)carve((size_t)9 * R * 2 * 4);  // 9 slots: h0..h8 (sum,sumsq)

  fold_blk<<<L * HDIM, 256, 0, stream>>>(bg, bb, bw, bbias, bfold, Sfold);
  fold_pack<<<(L * 131072) / 256, 256, 0, stream>>>(bg, bw, Wfrag);
  fold_head<<<1, 256, 0, stream>>>(lg, lb, lw, lbias, headW, headAux);
  fold_stem<<<HDIM * 64 / 256, 256, 0, stream>>>(stw, Wst);

  const int nstats = 9 * R * 2;
  for (int c = 0; c < B / R; ++c) {
    int rowBase = c * R;
    zero_f32<<<(nstats + 255) / 256, 256, 0, stream>>>(stats, nstats);
    {
      dim3 grid(R / 128, 8);
      stem_gemm<<<grid, 256, 0, stream>>>(x, stg, stb, Wst, stbias, hA, stats, rowBase);
    }
    _Float16* cur = hA;
    _Float16* nxt = hB;
    for (int lyr = 0; lyr < L; ++lyr) {
      int nb = (R / 128) * 4;
      layer_gemm<<<nb, 256, 0, stream>>>(
          cur, stats + (size_t)lyr * R * 2, Wfrag + (size_t)lyr * HDIM * HDIM,
          bfold + lyr * HDIM, Sfold + lyr * HDIM, nxt, stats + (size_t)(lyr + 1) * R * 2);
      _Float16* tmp = cur; cur = nxt; nxt = tmp;
    }
    head_kernel<<<R / 8, 512, 0, stream>>>(cur, stats + (size_t)8 * R * 2, headW, headAux, out, rowBase);
  }
}